// Round 2
// baseline (885.523 us; speedup 1.0000x reference)
//
#include <hip/hip_runtime.h>
#include <hip/hip_bf16.h>
#include <math.h>

#define DDIM 7168
#define NEXP 256
#define NGRP 8
#define TOPKG 4
#define TOPK 8
#define ROUTE_SCALE 2.5f

#define BM 32
#define BK 32

// Kernel 1: s = sigmoid(x @ w^T), fp32 VALU GEMM.
// grid = B/32 blocks of 128 threads; each block: 32 rows x 256 experts.
// 8x8 register tile per thread; LDS staged transposed ([k][m], [k][e]).
__global__ __launch_bounds__(128) void gemm_sig_kernel(
    const float* __restrict__ x, const float* __restrict__ w,
    float* __restrict__ s)
{
    __shared__ float xs[BK][BM];     // 4 KB
    __shared__ float wl[BK][NEXP];   // 32 KB
    const int t = threadIdx.x;
    const int brow = blockIdx.x * BM;
    const int trb = (t >> 5) << 3;   // row offset within tile: 0,8,16,24
    const int tcb = (t & 31) << 3;   // expert offset: 0..248

    float acc[8][8];
    #pragma unroll
    for (int i = 0; i < 8; i++)
        #pragma unroll
        for (int j = 0; j < 8; j++) acc[i][j] = 0.f;

    for (int k0 = 0; k0 < DDIM; k0 += BK) {
        __syncthreads();
        // stage x tile transposed: xs[k][row]
        #pragma unroll
        for (int si = 0; si < 2; si++) {
            int slot = t + si * 128;          // 256 slots = 32 rows x 8 float4-chunks
            int row  = slot >> 3;
            int kk   = (slot & 7) << 2;
            float4 v = *(const float4*)(x + (size_t)(brow + row) * DDIM + k0 + kk);
            xs[kk + 0][row] = v.x;
            xs[kk + 1][row] = v.y;
            xs[kk + 2][row] = v.z;
            xs[kk + 3][row] = v.w;
        }
        // stage w tile transposed: wl[k][e]; thread t owns experts t and t+128
        #pragma unroll
        for (int si = 0; si < 2; si++) {
            int e = t + si * 128;
            const float* wp = w + (size_t)e * DDIM + k0;
            #pragma unroll
            for (int kk = 0; kk < BK; kk += 4) {
                float4 v = *(const float4*)(wp + kk);
                wl[kk + 0][e] = v.x;
                wl[kk + 1][e] = v.y;
                wl[kk + 2][e] = v.z;
                wl[kk + 3][e] = v.w;
            }
        }
        __syncthreads();
        #pragma unroll
        for (int k = 0; k < BK; k++) {
            float a[8], b[8];
            *(float4*)&a[0] = *(const float4*)&xs[k][trb];
            *(float4*)&a[4] = *(const float4*)&xs[k][trb + 4];
            *(float4*)&b[0] = *(const float4*)&wl[k][tcb];
            *(float4*)&b[4] = *(const float4*)&wl[k][tcb + 4];
            #pragma unroll
            for (int i = 0; i < 8; i++)
                #pragma unroll
                for (int j = 0; j < 8; j++)
                    acc[i][j] = fmaf(a[i], b[j], acc[i][j]);
        }
    }
    // epilogue: sigmoid + store
    #pragma unroll
    for (int i = 0; i < 8; i++) {
        float tmp[8];
        #pragma unroll
        for (int j = 0; j < 8; j++)
            tmp[j] = 1.0f / (1.0f + expf(-acc[i][j]));
        float* op = s + (size_t)(brow + trb + i) * NEXP + tcb;
        *(float4*)(op)     = *(const float4*)&tmp[0];
        *(float4*)(op + 4) = *(const float4*)&tmp[4];
    }
}

// Kernel 2: full gating pipeline, one wave64 per row.
// lane l owns experts 4l..4l+3; group g = experts 32g..32g+31 = lanes 8g..8g+7.
__global__ __launch_bounds__(256) void gate_kernel(
    const float* __restrict__ s, const float* __restrict__ bias,
    float* __restrict__ out_w, float* __restrict__ out_i, int B)
{
    const int lane = threadIdx.x & 63;
    const int wid  = threadIdx.x >> 6;
    const int row  = blockIdx.x * 4 + wid;
    if (row >= B) return;

    const float* sr = s + (size_t)row * NEXP;
    float4 sv = *(const float4*)(sr + lane * 4);
    float4 bv = *(const float4*)(bias + lane * 4);
    float so[4] = { sv.x, sv.y, sv.z, sv.w };                         // original sigmoid
    float sb[4] = { sv.x + bv.x, sv.y + bv.y, sv.z + bv.z, sv.w + bv.w }; // bias-corrected

    // ---- group scores: sum of top-2 of sb within each 32-expert group ----
    float m1 = sb[0], m2 = -INFINITY;
    #pragma unroll
    for (int j = 1; j < 4; j++) {
        if (sb[j] > m1)      { m2 = m1; m1 = sb[j]; }
        else if (sb[j] > m2) { m2 = sb[j]; }
    }
    // merge (m1,m2) pairs across the 8 lanes of the group (xor 1,2,4)
    #pragma unroll
    for (int m = 1; m <= 4; m <<= 1) {
        float o1 = __shfl_xor(m1, m);
        float o2 = __shfl_xor(m2, m);
        float hi = fmaxf(m1, o1);
        float lo = fminf(m1, o1);
        m1 = hi;
        m2 = fmaxf(lo, fmaxf(m2, o2));
    }
    float gscore = m1 + m2;
    int g = lane >> 3;

    // ---- top-4 groups (tie-break: lower group index wins, matching top_k) ----
    float gs[NGRP];
    #pragma unroll
    for (int gg = 0; gg < NGRP; gg++) gs[gg] = __shfl(gscore, gg * 8);
    int rank = 0;
    #pragma unroll
    for (int gg = 0; gg < NGRP; gg++) {
        if (gg == g) continue;
        if (gs[gg] > gs[g] || (gs[gg] == gs[g] && gg < g)) rank++;
    }
    const bool selg = (rank < TOPKG);
    float mv[4];
    #pragma unroll
    for (int j = 0; j < 4; j++) mv[j] = selg ? sb[j] : -INFINITY;

    // ---- iterative top-8 wave argmax (value desc, index asc) ----
    float wsel[TOPK];
    int   isel[TOPK];
    float wsum = 0.f;
    #pragma unroll
    for (int it = 0; it < TOPK; it++) {
        float v = mv[0]; int jj = 0;
        #pragma unroll
        for (int j = 1; j < 4; j++)
            if (mv[j] > v) { v = mv[j]; jj = j; }   // strict > keeps lower j on tie
        int gi = (lane << 2) | jj;
        #pragma unroll
        for (int m = 1; m < 64; m <<= 1) {
            float ov = __shfl_xor(v, m);
            int   oi = __shfl_xor(gi, m);
            if (ov > v || (ov == v && oi < gi)) { v = ov; gi = oi; }
        }
        // gi is the global winner (uniform across lanes)
        int slot = gi & 3, src = gi >> 2;
        float cand = (slot == 0) ? so[0] : (slot == 1) ? so[1] : (slot == 2) ? so[2] : so[3];
        float sval = __shfl(cand, src);             // original sigmoid score at winner
        wsel[it] = sval; isel[it] = gi; wsum += sval;
        if (lane == src) mv[slot] = -INFINITY;      // remove winner
    }

    if (lane == 0) {
        float scl = ROUTE_SCALE / wsum;
        #pragma unroll
        for (int it = 0; it < TOPK; it++) {
            out_w[(size_t)row * TOPK + it] = wsel[it] * scl;
            out_i[(size_t)row * TOPK + it] = (float)isel[it];  // indices as float values
        }
    }
}

extern "C" void kernel_launch(void* const* d_in, const int* in_sizes, int n_in,
                              void* d_out, int out_size, void* d_ws, size_t ws_size,
                              hipStream_t stream)
{
    const float* x    = (const float*)d_in[0];
    const float* w    = (const float*)d_in[1];
    const float* bias = (const float*)d_in[2];
    const int B = in_sizes[0] / DDIM;            // 8192

    float* s = (float*)d_ws;                     // B x 256 sigmoid scores (8 MB)
    float* out_w = (float*)d_out;                // B x 8 weights
    float* out_i = out_w + (size_t)B * TOPK;     // B x 8 indices (as floats)

    dim3 g1(B / BM), b1(128);
    hipLaunchKernelGGL(gemm_sig_kernel, g1, b1, 0, stream, x, w, s);

    dim3 g2((B + 3) / 4), b2(256);
    hipLaunchKernelGGL(gate_kernel, g2, b2, 0, stream, s, bias, out_w, out_i, B);
}

// Round 3
// 201.368 us; speedup vs baseline: 4.3975x; 4.3975x over previous
//
#include <hip/hip_runtime.h>
#include <hip/hip_bf16.h>
#include <math.h>

#define DDIM 7168
#define NEXP 256
#define NGRP 8
#define TOPKG 4
#define TOPK 8
#define ROUTE_SCALE 2.5f

#define BM 128
#define BK 32
#define KSPLIT 4
#define KPER (DDIM / KSPLIT)        // 1792
#define NSTEP (KPER / BK)           // 56
#define NKTILE (DDIM / BK)          // 224
#define BTILE_ELEMS (NEXP * BK * 2) // 16384 bf16 elems = 32 KB per k-step tile

typedef __attribute__((ext_vector_type(8))) short bf16x8;
typedef __attribute__((ext_vector_type(4))) float f32x4;
typedef unsigned int u32;
typedef unsigned short ushort_t;

static __device__ __forceinline__ ushort_t bf16_rne(float f) {
    u32 b = __float_as_uint(f);
    u32 r = (b + 0x7fffu + ((b >> 16) & 1u)) >> 16;
    return (ushort_t)r;
}
static __device__ __forceinline__ float bf16_to_f32(ushort_t h) {
    return __uint_as_float(((u32)h) << 16);
}

// ---------------------------------------------------------------------------
// Kernel 0: split w into hi/lo bf16, repacked fragment-linear per BK-step tile.
// Tile layout (32 KB): [split(2)][fn(16)][lane(64)][8 bf16]
// element (split,fn,lane,j) = split-part of w[fn*16 + (lane&15)][ks*32 + (lane>>4)*8 + j]
// => B-fragment reads in the GEMM are lane-linear 16B (conflict-free), and
//    global_load_lds staging is a straight linear copy.
// ---------------------------------------------------------------------------
__global__ __launch_bounds__(256) void wsplit_kernel(const float* __restrict__ w,
                                                     short* __restrict__ wsp)
{
    const int ks = blockIdx.x;      // 0..223
    const int e  = threadIdx.x;     // expert 0..255
    const float* wp = w + (size_t)e * DDIM + (size_t)ks * BK;
    short* tb = wsp + (size_t)ks * BTILE_ELEMS;
    const int fn = e >> 4, er = e & 15;
    #pragma unroll
    for (int jg = 0; jg < 4; jg++) {
        float f[8];
        *(float4*)&f[0] = *(const float4*)(wp + jg * 8);
        *(float4*)&f[4] = *(const float4*)(wp + jg * 8 + 4);
        ushort_t h[8], l[8];
        #pragma unroll
        for (int j = 0; j < 8; j++) {
            h[j] = bf16_rne(f[j]);
            float rem = f[j] - bf16_to_f32(h[j]);
            l[j] = bf16_rne(rem);
        }
        const int lane = jg * 16 + er;
        *(uint4*)(tb + ((size_t)(0 * 16 + fn) * 64 + lane) * 8) = *(uint4*)h;
        *(uint4*)(tb + ((size_t)(1 * 16 + fn) * 64 + lane) * 8) = *(uint4*)l;
    }
}

// ---------------------------------------------------------------------------
// Kernel 1: split-precision bf16 MFMA GEMM, partial sums per split-K plane.
// grid = (B/128) * 4 ; 512 threads = 8 waves (2 wm x 4 wn), wave tile 64x64.
// A: per-wave global fp32 loads -> in-register hi/lo split (no LDS, no barrier dep).
// B: global_load_lds double-buffer, ONE barrier per K-step.
// ---------------------------------------------------------------------------
__global__ __launch_bounds__(512, 2) void gemm_split_kernel(
    const float* __restrict__ x, const short* __restrict__ wsp,
    float* __restrict__ part, int Btok)
{
    __shared__ short Blds[2][BTILE_ELEMS];   // 2 x 32 KB = 64 KB

    const int bid  = blockIdx.x;
    const int mt   = bid >> 2;               // 0..63
    const int ksp  = bid & 3;                // split-K id
    const int m0   = mt * BM;
    const int kbase = ksp * KPER;
    const int t    = threadIdx.x;
    const int wid  = t >> 6, lane = t & 63;
    const int wm   = wid >> 2, wn = wid & 3;
    const int lr   = lane & 15, lg = lane >> 4;

    // A base: row = m0 + wm*64 + fm*16 + lr ; k = kbase + st*32 + lg*8
    const float* abase = x + (size_t)(m0 + wm * 64 + lr) * DDIM + kbase + lg * 8;
    const short* wt_base = wsp + (size_t)(ksp * NSTEP) * BTILE_ELEMS;

    f32x4 acc[4][4];
    #pragma unroll
    for (int i = 0; i < 4; i++)
        #pragma unroll
        for (int j = 0; j < 4; j++) acc[i][j] = (f32x4){0.f, 0.f, 0.f, 0.f};

    // ---- prologue: issue B(0) staging + load A(0) regs ----
    {
        const short* gt = wt_base;
        #pragma unroll
        for (int i = 0; i < 4; i++) {
            const int off = wid * 4096 + i * 1024;
            __builtin_amdgcn_global_load_lds(
                (const __attribute__((address_space(1))) u32*)((const char*)gt + off + lane * 16),
                (__attribute__((address_space(3))) u32*)((char*)&Blds[0][0] + off),
                16, 0, 0);
        }
    }
    float a_cur[4][8];
    #pragma unroll
    for (int fm = 0; fm < 4; fm++) {
        const float* ap = abase + (size_t)fm * 16 * DDIM;
        *(float4*)&a_cur[fm][0] = *(const float4*)(ap);
        *(float4*)&a_cur[fm][4] = *(const float4*)(ap + 4);
    }

    #pragma unroll 2
    for (int st = 0; st < NSTEP; st++) {
        const int p = st & 1;
        // barrier: (a) drains vmcnt -> B(st) resident in Blds[p];
        //          (b) all waves finished reading Blds[p^1] (step st-1).
        __syncthreads();

        // ---- issue next-step loads (land during this step's MFMAs) ----
        float a_nxt[4][8];
        if (st + 1 < NSTEP) {
            const short* gt = wt_base + (size_t)(st + 1) * BTILE_ELEMS;
            #pragma unroll
            for (int i = 0; i < 4; i++) {
                const int off = wid * 4096 + i * 1024;
                __builtin_amdgcn_global_load_lds(
                    (const __attribute__((address_space(1))) u32*)((const char*)gt + off + lane * 16),
                    (__attribute__((address_space(3))) u32*)((char*)&Blds[p ^ 1][0] + off),
                    16, 0, 0);
            }
            #pragma unroll
            for (int fm = 0; fm < 4; fm++) {
                const float* ap = abase + (size_t)fm * 16 * DDIM + (size_t)(st + 1) * BK;
                *(float4*)&a_nxt[fm][0] = *(const float4*)(ap);
                *(float4*)&a_nxt[fm][4] = *(const float4*)(ap + 4);
            }
        }

        // ---- convert A(st) to hi/lo bf16 fragments (in-register) ----
        bf16x8 ah[4], al[4];
        #pragma unroll
        for (int fm = 0; fm < 4; fm++) {
            union { bf16x8 v; short s[8]; } H, L;
            #pragma unroll
            for (int j = 0; j < 8; j++) {
                const float f = a_cur[fm][j];
                const ushort_t hb = bf16_rne(f);
                const float rem = f - bf16_to_f32(hb);
                H.s[j] = (short)hb;
                L.s[j] = (short)bf16_rne(rem);
            }
            ah[fm] = H.v;
            al[fm] = L.v;
        }

        // ---- MFMA: C += Ah*Bh + Ah*Bl + Al*Bh ----
        #pragma unroll
        for (int fn = 0; fn < 4; fn++) {
            const bf16x8 bh = *(const bf16x8*)&Blds[p][((size_t)(0 * 16 + wn * 4 + fn) * 64 + lane) * 8];
            const bf16x8 bl = *(const bf16x8*)&Blds[p][((size_t)(1 * 16 + wn * 4 + fn) * 64 + lane) * 8];
            #pragma unroll
            for (int fm = 0; fm < 4; fm++) {
                acc[fm][fn] = __builtin_amdgcn_mfma_f32_16x16x32_bf16(ah[fm], bh, acc[fm][fn], 0, 0, 0);
                acc[fm][fn] = __builtin_amdgcn_mfma_f32_16x16x32_bf16(ah[fm], bl, acc[fm][fn], 0, 0, 0);
                acc[fm][fn] = __builtin_amdgcn_mfma_f32_16x16x32_bf16(al[fm], bh, acc[fm][fn], 0, 0, 0);
            }
        }

        if (st + 1 < NSTEP) {
            #pragma unroll
            for (int fm = 0; fm < 4; fm++)
                #pragma unroll
                for (int j = 0; j < 8; j++) a_cur[fm][j] = a_nxt[fm][j];
        }
    }

    // ---- epilogue: write fp32 partials ----
    // C/D mapping (verified m89): col = lane&15, row = (lane>>4)*4 + reg
    float* pp = part + (size_t)ksp * (size_t)Btok * NEXP;
    #pragma unroll
    for (int fm = 0; fm < 4; fm++) {
        const int row0 = m0 + wm * 64 + fm * 16 + lg * 4;
        #pragma unroll
        for (int fn = 0; fn < 4; fn++) {
            const int col = wn * 64 + fn * 16 + lr;
            #pragma unroll
            for (int rr = 0; rr < 4; rr++)
                pp[(size_t)(row0 + rr) * NEXP + col] = acc[fm][fn][rr];
        }
    }
}

// ---------------------------------------------------------------------------
// Kernel 2: reduce split-K partials + sigmoid + full gating, one wave per row.
// ---------------------------------------------------------------------------
__global__ __launch_bounds__(256) void gate_kernel(
    const float* __restrict__ part, const float* __restrict__ bias,
    float* __restrict__ out_w, float* __restrict__ out_i, int B)
{
    const int lane = threadIdx.x & 63;
    const int wid  = threadIdx.x >> 6;
    const int row  = blockIdx.x * 4 + wid;
    if (row >= B) return;

    const size_t plane = (size_t)B * NEXP;
    const float* pr = part + (size_t)row * NEXP + lane * 4;
    float4 v0 = *(const float4*)(pr);
    float4 v1 = *(const float4*)(pr + plane);
    float4 v2 = *(const float4*)(pr + 2 * plane);
    float4 v3 = *(const float4*)(pr + 3 * plane);
    float sc[4] = { v0.x + v1.x + v2.x + v3.x,
                    v0.y + v1.y + v2.y + v3.y,
                    v0.z + v1.z + v2.z + v3.z,
                    v0.w + v1.w + v2.w + v3.w };
    float4 bv = *(const float4*)(bias + lane * 4);
    const float bb[4] = { bv.x, bv.y, bv.z, bv.w };

    float so[4], sb[4];
    #pragma unroll
    for (int j = 0; j < 4; j++) {
        so[j] = 1.0f / (1.0f + expf(-sc[j]));  // original sigmoid score
        sb[j] = so[j] + bb[j];                 // bias-corrected
    }

    // ---- group scores: sum of top-2 of sb within each 32-expert group ----
    float m1 = sb[0], m2 = -INFINITY;
    #pragma unroll
    for (int j = 1; j < 4; j++) {
        if (sb[j] > m1)      { m2 = m1; m1 = sb[j]; }
        else if (sb[j] > m2) { m2 = sb[j]; }
    }
    #pragma unroll
    for (int m = 1; m <= 4; m <<= 1) {
        float o1 = __shfl_xor(m1, m);
        float o2 = __shfl_xor(m2, m);
        float hi = fmaxf(m1, o1);
        float lo = fminf(m1, o1);
        m1 = hi;
        m2 = fmaxf(lo, fmaxf(m2, o2));
    }
    float gscore = m1 + m2;
    int g = lane >> 3;

    // ---- top-4 groups (value desc, index asc) ----
    float gs[NGRP];
    #pragma unroll
    for (int gg = 0; gg < NGRP; gg++) gs[gg] = __shfl(gscore, gg * 8);
    int rank = 0;
    #pragma unroll
    for (int gg = 0; gg < NGRP; gg++) {
        if (gg == g) continue;
        if (gs[gg] > gs[g] || (gs[gg] == gs[g] && gg < g)) rank++;
    }
    const bool selg = (rank < TOPKG);
    float mv[4];
    #pragma unroll
    for (int j = 0; j < 4; j++) mv[j] = selg ? sb[j] : -INFINITY;

    // ---- iterative top-8 wave argmax (value desc, index asc) ----
    float wsel[TOPK];
    int   isel[TOPK];
    float wsum = 0.f;
    #pragma unroll
    for (int it = 0; it < TOPK; it++) {
        float v = mv[0]; int jj = 0;
        #pragma unroll
        for (int j = 1; j < 4; j++)
            if (mv[j] > v) { v = mv[j]; jj = j; }
        int gi = (lane << 2) | jj;
        #pragma unroll
        for (int m = 1; m < 64; m <<= 1) {
            float ov = __shfl_xor(v, m);
            int   oi = __shfl_xor(gi, m);
            if (ov > v || (ov == v && oi < gi)) { v = ov; gi = oi; }
        }
        int slot = gi & 3, src = gi >> 2;
        float cand = (slot == 0) ? so[0] : (slot == 1) ? so[1] : (slot == 2) ? so[2] : so[3];
        float sval = __shfl(cand, src);
        wsel[it] = sval; isel[it] = gi; wsum += sval;
        if (lane == src) mv[slot] = -INFINITY;
    }

    if (lane == 0) {
        float scl = ROUTE_SCALE / wsum;
        #pragma unroll
        for (int it = 0; it < TOPK; it++) {
            out_w[(size_t)row * TOPK + it] = wsel[it] * scl;
            out_i[(size_t)row * TOPK + it] = (float)isel[it];
        }
    }
}

extern "C" void kernel_launch(void* const* d_in, const int* in_sizes, int n_in,
                              void* d_out, int out_size, void* d_ws, size_t ws_size,
                              hipStream_t stream)
{
    const float* x    = (const float*)d_in[0];
    const float* w    = (const float*)d_in[1];
    const float* bias = (const float*)d_in[2];
    const int B = in_sizes[0] / DDIM;           // 8192

    // ws layout: [ part: KSPLIT * B * 256 f32 = 32 MB ][ wsp: 224 * 32 KB = 7.34 MB ]
    float* part = (float*)d_ws;
    short* wsp  = (short*)((char*)d_ws + (size_t)KSPLIT * B * NEXP * sizeof(float));

    float* out_w = (float*)d_out;
    float* out_i = out_w + (size_t)B * TOPK;

    hipLaunchKernelGGL(wsplit_kernel, dim3(NKTILE), dim3(256), 0, stream, w, wsp);
    hipLaunchKernelGGL(gemm_split_kernel, dim3((B / BM) * KSPLIT), dim3(512), 0, stream,
                       x, wsp, part, B);
    hipLaunchKernelGGL(gate_kernel, dim3((B + 3) / 4), dim3(256), 0, stream,
                       part, bias, out_w, out_i, B);
}

// Round 6
// 181.152 us; speedup vs baseline: 4.8883x; 1.1116x over previous
//
#include <hip/hip_runtime.h>
#include <hip/hip_bf16.h>
#include <math.h>

#define DDIM 7168
#define NEXP 256
#define NGRP 8
#define TOPKG 4
#define TOPK 8
#define ROUTE_SCALE 2.5f

#define BM 64
#define BN 128
#define BK 32
#define KSPLIT 4
#define KPER (DDIM / KSPLIT)     // 1792
#define NSTEP (KPER / BK)        // 56
#define NKTILE (DDIM / BK)       // 224
#define BT_ELEMS (BN * BK * 2)   // 8192 shorts = 16 KB per (ks, nh) tile

typedef __attribute__((ext_vector_type(8))) short bf16x8;
typedef __attribute__((ext_vector_type(4))) float f32x4;
typedef unsigned int u32;
typedef unsigned short ushort_t;

static __device__ __forceinline__ ushort_t bf16_rne(float f) {
    u32 b = __float_as_uint(f);
    u32 r = (b + 0x7fffu + ((b >> 16) & 1u)) >> 16;
    return (ushort_t)r;
}
static __device__ __forceinline__ float bf16_to_f32(ushort_t h) {
    return __uint_as_float(((u32)h) << 16);
}
// hi = bf16_rne(f) via HW cvt (compiler pairs into v_cvt_pk_bf16_f32); lo = bf16(f - hi)
static __device__ __forceinline__ void split_elem(float f, short& h, short& l) {
    union { __hip_bfloat16 b; short s; } cv;
    cv.b = __float2bfloat16(f);
    h = cv.s;
    float hf = __uint_as_float(((u32)(ushort_t)cv.s) << 16);
    cv.b = __float2bfloat16(f - hf);
    l = cv.s;
}

// ---------------------------------------------------------------------------
// Kernel 0: split w into hi/lo bf16, fragment-linear tiles per (ks, nh).
// Tile (16 KB): [split(2)][fn(8)][lane(64)][8 bf16]
// element (split,fn,lane,j) = split of W[nh*128 + fn*16 + (lane&15)][ks*32 + (lane>>4)*8 + j]
// ---------------------------------------------------------------------------
__global__ __launch_bounds__(256) void wsplit_kernel(const float* __restrict__ w,
                                                     short* __restrict__ wsp)
{
    const int ks = blockIdx.x;      // 0..223
    const int e  = threadIdx.x;     // expert 0..255
    const float* wp = w + (size_t)e * DDIM + (size_t)ks * BK;
    const int nh = e >> 7, fn = (e >> 4) & 7, er = e & 15;
    short* tb = wsp + ((size_t)ks * 2 + nh) * BT_ELEMS;
    #pragma unroll
    for (int jg = 0; jg < 4; jg++) {   // k-chunk: k = jg*8 .. jg*8+7  (lane>>4 == jg)
        float f[8];
        *(float4*)&f[0] = *(const float4*)(wp + jg * 8);
        *(float4*)&f[4] = *(const float4*)(wp + jg * 8 + 4);
        ushort_t h[8], l[8];
        #pragma unroll
        for (int j = 0; j < 8; j++) {
            h[j] = bf16_rne(f[j]);
            l[j] = bf16_rne(f[j] - bf16_to_f32(h[j]));
        }
        const int lane = jg * 16 + er;
        *(uint4*)(tb + ((size_t)(0 * 8 + fn) * 64 + lane) * 8) = *(uint4*)h;
        *(uint4*)(tb + ((size_t)(1 * 8 + fn) * 64 + lane) * 8) = *(uint4*)l;
    }
}

// ---------------------------------------------------------------------------
// Kernel 1: split-precision bf16 MFMA GEMM (R3-proven structure, retiled).
// grid = 128 mt x 2 nh x 4 ksp = 1024 blocks (4/CU); 256 thr = 4 waves
// (2 wm x 2 wn), wave tile 32x64. A: per-wave global fp32 loads -> in-reg
// hi/lo split (R3 pattern, correctness-proven). B: global_load_lds dbuf,
// one __syncthreads per K-step. LDS 32 KB -> 4 blocks/CU co-resident.
// ---------------------------------------------------------------------------
__global__ __launch_bounds__(256, 4) void gemm_split_kernel(
    const float* __restrict__ x, const short* __restrict__ wsp,
    float* __restrict__ part, int Btok)
{
    __shared__ short Blds[2][BT_ELEMS];   // 2 x 16 KB

    const int bid  = blockIdx.x;
    const int mt   = bid >> 3;            // 0..127
    const int nh   = (bid >> 2) & 1;
    const int ksp  = bid & 3;
    const int m0   = mt * BM;
    const int kbase = ksp * KPER;
    const int t    = threadIdx.x;
    const int wid  = t >> 6, lane = t & 63;
    const int wm   = wid >> 1, wn = wid & 1;
    const int lr   = lane & 15, lg = lane >> 4;

    // B tile for step st lives at wsp[((ksp*NSTEP + st)*2 + nh) * BT_ELEMS]
    const short* wt0 = wsp + ((size_t)(ksp * NSTEP) * 2 + nh) * BT_ELEMS;
    // A: wave (wm,*) rows m0 + wm*32 + fm*16 + (lane&15); k = kbase + st*32 + lg*8
    const float* abase = x + (size_t)(m0 + wm * 32 + lr) * DDIM + kbase + lg * 8;

    f32x4 acc[2][4];
    #pragma unroll
    for (int i = 0; i < 2; i++)
        #pragma unroll
        for (int j = 0; j < 4; j++) acc[i][j] = (f32x4){0.f, 0.f, 0.f, 0.f};

    // ---- prologue: issue B(0) staging + load A(0) regs ----
    {
        #pragma unroll
        for (int i = 0; i < 4; i++) {
            const int off = wid * 4096 + i * 1024;
            __builtin_amdgcn_global_load_lds(
                (const __attribute__((address_space(1))) u32*)((const char*)wt0 + off + lane * 16),
                (__attribute__((address_space(3))) u32*)((char*)&Blds[0][0] + off),
                16, 0, 0);
        }
    }
    float a_cur[2][8];
    #pragma unroll
    for (int fm = 0; fm < 2; fm++) {
        const float* ap = abase + (size_t)fm * 16 * DDIM;
        *(float4*)&a_cur[fm][0] = *(const float4*)(ap);
        *(float4*)&a_cur[fm][4] = *(const float4*)(ap + 4);
    }

    #pragma unroll 2
    for (int st = 0; st < NSTEP; st++) {
        const int cur = st & 1;
        // drains B(st) DMA (issued one full step ago) + all waves' prior reads
        __syncthreads();

        // ---- issue next-step loads (land during this step's MFMAs) ----
        float a_nxt[2][8];
        if (st + 1 < NSTEP) {
            const short* gt = wt0 + (size_t)(st + 1) * 2 * BT_ELEMS;
            short* bdst = &Blds[cur ^ 1][0];
            #pragma unroll
            for (int i = 0; i < 4; i++) {
                const int off = wid * 4096 + i * 1024;
                __builtin_amdgcn_global_load_lds(
                    (const __attribute__((address_space(1))) u32*)((const char*)gt + off + lane * 16),
                    (__attribute__((address_space(3))) u32*)((char*)bdst + off),
                    16, 0, 0);
            }
            #pragma unroll
            for (int fm = 0; fm < 2; fm++) {
                const float* ap = abase + (size_t)fm * 16 * DDIM + (size_t)(st + 1) * BK;
                *(float4*)&a_nxt[fm][0] = *(const float4*)(ap);
                *(float4*)&a_nxt[fm][4] = *(const float4*)(ap + 4);
            }
        }

        // ---- convert A(st) to hi/lo bf16 fragments (in-register, HW cvt) ----
        bf16x8 ah[2], al[2];
        #pragma unroll
        for (int fm = 0; fm < 2; fm++) {
            union { bf16x8 v; short s[8]; } H, L;
            #pragma unroll
            for (int j = 0; j < 8; j++)
                split_elem(a_cur[fm][j], H.s[j], L.s[j]);
            ah[fm] = H.v;
            al[fm] = L.v;
        }

        // ---- MFMA: C += Ah*Bh + Ah*Bl + Al*Bh ----
        #pragma unroll
        for (int fn = 0; fn < 4; fn++) {
            const bf16x8 bh = *(const bf16x8*)&Blds[cur][((size_t)(0 * 8 + wn * 4 + fn) * 64 + lane) * 8];
            const bf16x8 bl = *(const bf16x8*)&Blds[cur][((size_t)(1 * 8 + wn * 4 + fn) * 64 + lane) * 8];
            #pragma unroll
            for (int fm = 0; fm < 2; fm++) {
                acc[fm][fn] = __builtin_amdgcn_mfma_f32_16x16x32_bf16(ah[fm], bh, acc[fm][fn], 0, 0, 0);
                acc[fm][fn] = __builtin_amdgcn_mfma_f32_16x16x32_bf16(ah[fm], bl, acc[fm][fn], 0, 0, 0);
                acc[fm][fn] = __builtin_amdgcn_mfma_f32_16x16x32_bf16(al[fm], bh, acc[fm][fn], 0, 0, 0);
            }
        }

        if (st + 1 < NSTEP) {
            #pragma unroll
            for (int fm = 0; fm < 2; fm++)
                #pragma unroll
                for (int j = 0; j < 8; j++) a_cur[fm][j] = a_nxt[fm][j];
        }
    }

    // ---- epilogue: fp32 partials (C/D map: col=lane&15, row=(lane>>4)*4+reg) ----
    float* pp = part + (size_t)ksp * (size_t)Btok * NEXP;
    #pragma unroll
    for (int fm = 0; fm < 2; fm++) {
        const int row0 = m0 + wm * 32 + fm * 16 + lg * 4;
        #pragma unroll
        for (int fn = 0; fn < 4; fn++) {
            const int col = nh * 128 + wn * 64 + fn * 16 + lr;
            #pragma unroll
            for (int rr = 0; rr < 4; rr++)
                pp[(size_t)(row0 + rr) * NEXP + col] = acc[fm][fn][rr];
        }
    }
}

// ---------------------------------------------------------------------------
// Kernel 2: reduce split-K partials + sigmoid + full gating, one wave per row.
// (unchanged from R3 — proven)
// ---------------------------------------------------------------------------
__global__ __launch_bounds__(256) void gate_kernel(
    const float* __restrict__ part, const float* __restrict__ bias,
    float* __restrict__ out_w, float* __restrict__ out_i, int B)
{
    const int lane = threadIdx.x & 63;
    const int wid  = threadIdx.x >> 6;
    const int row  = blockIdx.x * 4 + wid;
    if (row >= B) return;

    const size_t plane = (size_t)B * NEXP;
    const float* pr = part + (size_t)row * NEXP + lane * 4;
    float4 v0 = *(const float4*)(pr);
    float4 v1 = *(const float4*)(pr + plane);
    float4 v2 = *(const float4*)(pr + 2 * plane);
    float4 v3 = *(const float4*)(pr + 3 * plane);
    float sc[4] = { v0.x + v1.x + v2.x + v3.x,
                    v0.y + v1.y + v2.y + v3.y,
                    v0.z + v1.z + v2.z + v3.z,
                    v0.w + v1.w + v2.w + v3.w };
    float4 bv = *(const float4*)(bias + lane * 4);
    const float bb[4] = { bv.x, bv.y, bv.z, bv.w };

    float so[4], sb[4];
    #pragma unroll
    for (int j = 0; j < 4; j++) {
        so[j] = 1.0f / (1.0f + expf(-sc[j]));
        sb[j] = so[j] + bb[j];
    }

    // ---- group scores: sum of top-2 of sb within each 32-expert group ----
    float m1 = sb[0], m2 = -INFINITY;
    #pragma unroll
    for (int j = 1; j < 4; j++) {
        if (sb[j] > m1)      { m2 = m1; m1 = sb[j]; }
        else if (sb[j] > m2) { m2 = sb[j]; }
    }
    #pragma unroll
    for (int m = 1; m <= 4; m <<= 1) {
        float o1 = __shfl_xor(m1, m);
        float o2 = __shfl_xor(m2, m);
        float hi = fmaxf(m1, o1);
        float lo = fminf(m1, o1);
        m1 = hi;
        m2 = fmaxf(lo, fmaxf(m2, o2));
    }
    float gscore = m1 + m2;
    int g = lane >> 3;

    // ---- top-4 groups (value desc, index asc) ----
    float gs[NGRP];
    #pragma unroll
    for (int gg = 0; gg < NGRP; gg++) gs[gg] = __shfl(gscore, gg * 8);
    int rank = 0;
    #pragma unroll
    for (int gg = 0; gg < NGRP; gg++) {
        if (gg == g) continue;
        if (gs[gg] > gs[g] || (gs[gg] == gs[g] && gg < g)) rank++;
    }
    const bool selg = (rank < TOPKG);
    float mv[4];
    #pragma unroll
    for (int j = 0; j < 4; j++) mv[j] = selg ? sb[j] : -INFINITY;

    // ---- iterative top-8 wave argmax (value desc, index asc) ----
    float wsel[TOPK];
    int   isel[TOPK];
    float wsum = 0.f;
    #pragma unroll
    for (int it = 0; it < TOPK; it++) {
        float v = mv[0]; int jj = 0;
        #pragma unroll
        for (int j = 1; j < 4; j++)
            if (mv[j] > v) { v = mv[j]; jj = j; }
        int gi = (lane << 2) | jj;
        #pragma unroll
        for (int m = 1; m < 64; m <<= 1) {
            float ov = __shfl_xor(v, m);
            int   oi = __shfl_xor(gi, m);
            if (ov > v || (ov == v && oi < gi)) { v = ov; gi = oi; }
        }
        int slot = gi & 3, src = gi >> 2;
        float cand = (slot == 0) ? so[0] : (slot == 1) ? so[1] : (slot == 2) ? so[2] : so[3];
        float sval = __shfl(cand, src);
        wsel[it] = sval; isel[it] = gi; wsum += sval;
        if (lane == src) mv[slot] = -INFINITY;
    }

    if (lane == 0) {
        float scl = ROUTE_SCALE / wsum;
        #pragma unroll
        for (int it = 0; it < TOPK; it++) {
            out_w[(size_t)row * TOPK + it] = wsel[it] * scl;
            out_i[(size_t)row * TOPK + it] = (float)isel[it];
        }
    }
}

extern "C" void kernel_launch(void* const* d_in, const int* in_sizes, int n_in,
                              void* d_out, int out_size, void* d_ws, size_t ws_size,
                              hipStream_t stream)
{
    const float* x    = (const float*)d_in[0];
    const float* w    = (const float*)d_in[1];
    const float* bias = (const float*)d_in[2];
    const int B = in_sizes[0] / DDIM;           // 8192

    // ws layout: [ part: KSPLIT * B * 256 f32 = 32 MB ][ wsp: 224*2 tiles * 16 KB = 7.34 MB ]
    float* part = (float*)d_ws;
    short* wsp  = (short*)((char*)d_ws + (size_t)KSPLIT * B * NEXP * sizeof(float));

    float* out_w = (float*)d_out;
    float* out_i = out_w + (size_t)B * TOPK;

    hipLaunchKernelGGL(wsplit_kernel, dim3(NKTILE), dim3(256), 0, stream, w, wsp);
    hipLaunchKernelGGL(gemm_split_kernel, dim3((B / BM) * 2 * KSPLIT), dim3(256), 0, stream,
                       x, wsp, part, B);
    hipLaunchKernelGGL(gate_kernel, dim3((B + 3) / 4), dim3(256), 0, stream,
                       part, bias, out_w, out_i, B);
}

// Round 7
// 171.098 us; speedup vs baseline: 5.1755x; 1.0588x over previous
//
#include <hip/hip_runtime.h>
#include <hip/hip_bf16.h>
#include <math.h>

#define DDIM 7168
#define NEXP 256
#define NGRP 8
#define TOPKG 4
#define TOPK 8
#define ROUTE_SCALE 2.5f

#define BM 128
#define BN 128
#define BK 64
#define KSPLIT 4
#define KPER (DDIM / KSPLIT)     // 1792
#define NSTEP (KPER / BK)        // 28
#define NKT (DDIM / BK)          // 112 global k-tiles
#define BT_ELEMS (BN * BK * 2)   // 16384 shorts = 32 KB per (kt, nh) tile

typedef __attribute__((ext_vector_type(8))) short bf16x8;
typedef __attribute__((ext_vector_type(4))) float f32x4;
typedef unsigned int u32;
typedef unsigned short ushort_t;

static __device__ __forceinline__ ushort_t bf16_rne(float f) {
    u32 b = __float_as_uint(f);
    u32 r = (b + 0x7fffu + ((b >> 16) & 1u)) >> 16;
    return (ushort_t)r;
}
static __device__ __forceinline__ float bf16_to_f32(ushort_t h) {
    return __uint_as_float(((u32)h) << 16);
}
// hi = bf16(f) via HW cvt; lo = bf16(f - hi)
static __device__ __forceinline__ void split_elem(float f, short& h, short& l) {
    union { __hip_bfloat16 b; short s; } cv;
    cv.b = __float2bfloat16(f);
    h = cv.s;
    float hf = __uint_as_float(((u32)(ushort_t)cv.s) << 16);
    cv.b = __float2bfloat16(f - hf);
    l = cv.s;
}

// ---------------------------------------------------------------------------
// Kernel 0: split w into hi/lo bf16, fragment-linear tiles per (kt, nh).
// Tile (32 KB): [split(2)][ks(2)][fn(8)][lane(64)][8 bf16]
// element = split of W[nh*128 + fn*16 + (lane&15)][kt*64 + ks*32 + (lane>>4)*8 + j]
// grid = 112 (one block per kt); thread e = expert (nh = e>>7).
// ---------------------------------------------------------------------------
__global__ __launch_bounds__(256) void wsplit_kernel(const float* __restrict__ w,
                                                     short* __restrict__ wsp)
{
    const int kt = blockIdx.x;      // 0..111
    const int e  = threadIdx.x;     // expert 0..255
    const float* wp = w + (size_t)e * DDIM + (size_t)kt * BK;
    const int nh = e >> 7, fn = (e >> 4) & 7, er = e & 15;
    short* tb = wsp + ((size_t)kt * 2 + nh) * BT_ELEMS;
    #pragma unroll
    for (int ks = 0; ks < 2; ks++) {
        #pragma unroll
        for (int jg = 0; jg < 4; jg++) {   // k-octet within half: lane>>4 == jg
            float f[8];
            *(float4*)&f[0] = *(const float4*)(wp + ks * 32 + jg * 8);
            *(float4*)&f[4] = *(const float4*)(wp + ks * 32 + jg * 8 + 4);
            ushort_t h[8], l[8];
            #pragma unroll
            for (int j = 0; j < 8; j++) {
                h[j] = bf16_rne(f[j]);
                l[j] = bf16_rne(f[j] - bf16_to_f32(h[j]));
            }
            const int lane = jg * 16 + er;
            *(uint4*)(tb + ((size_t)((0 * 2 + ks) * 8 + fn) * 64 + lane) * 8) = *(uint4*)h;
            *(uint4*)(tb + ((size_t)((1 * 2 + ks) * 8 + fn) * 64 + lane) * 8) = *(uint4*)l;
        }
    }
}

// ---------------------------------------------------------------------------
// Kernel 1: split-precision bf16 MFMA GEMM, BK=64 (96 MFMA/wave/step to
// amortize the per-step barrier drain — R6 had 24 and was barrier-bound).
// grid = 64 mt x 2 nh x 4 ksp = 512 blocks (2/CU); 256 thr = 4 waves
// (2 wm x 2 wn), wave tile 64x64. A: per-wave global fp32 loads 1 step
// ahead -> in-reg hi/lo split (R3/R6-proven pattern). B: global_load_lds
// double-buffer, one __syncthreads per K-step. LDS 64 KB.
// ---------------------------------------------------------------------------
__global__ __launch_bounds__(256, 2) void gemm_split_kernel(
    const float* __restrict__ x, const short* __restrict__ wsp,
    float* __restrict__ part, int Btok)
{
    __shared__ short Blds[2][BT_ELEMS];   // 2 x 32 KB

    const int bid  = blockIdx.x;
    const int mt   = bid >> 3;            // 0..63
    const int nh   = (bid >> 2) & 1;
    const int ksp  = bid & 3;
    const int m0   = mt * BM;
    const int kbase = ksp * KPER;
    const int t    = threadIdx.x;
    const int wid  = t >> 6, lane = t & 63;
    const int wm   = wid >> 1, wn = wid & 1;
    const int lr   = lane & 15, lg = lane >> 4;

    // B tile for step st: wsp[(( (ksp*NSTEP+st)*2 ) + nh) * BT_ELEMS]
    const short* wt0 = wsp + ((size_t)(ksp * NSTEP) * 2 + nh) * BT_ELEMS;
    // A: rows m0 + wm*64 + fm*16 + lr ; k = kbase + st*64 + ks*32 + lg*8
    const float* abase = x + (size_t)(m0 + wm * 64 + lr) * DDIM + kbase + lg * 8;

    f32x4 acc[4][4];
    #pragma unroll
    for (int i = 0; i < 4; i++)
        #pragma unroll
        for (int j = 0; j < 4; j++) acc[i][j] = (f32x4){0.f, 0.f, 0.f, 0.f};

    float a_nxt[4][2][8];   // A(st) floats, loaded one step ahead

    // ---- prologue: issue B(0) staging + load A(0) regs ----
    #pragma unroll
    for (int i = 0; i < 8; i++) {
        const int off = wid * 8192 + i * 1024;
        __builtin_amdgcn_global_load_lds(
            (const __attribute__((address_space(1))) u32*)((const char*)wt0 + off + lane * 16),
            (__attribute__((address_space(3))) u32*)((char*)&Blds[0][0] + off),
            16, 0, 0);
    }
    #pragma unroll
    for (int fm = 0; fm < 4; fm++)
        #pragma unroll
        for (int ks = 0; ks < 2; ks++) {
            const float* ap = abase + (size_t)fm * 16 * DDIM + ks * 32;
            *(float4*)&a_nxt[fm][ks][0] = *(const float4*)(ap);
            *(float4*)&a_nxt[fm][ks][4] = *(const float4*)(ap + 4);
        }

    #pragma unroll 2
    for (int st = 0; st < NSTEP; st++) {
        const int cur = st & 1;
        // drains B(st) DMA + A(st) reg loads (issued one full step ago)
        __syncthreads();

        // ---- issue B(st+1) staging first (no reg deps) ----
        if (st + 1 < NSTEP) {
            const short* gt = wt0 + (size_t)(st + 1) * 2 * BT_ELEMS;
            short* bdst = &Blds[cur ^ 1][0];
            #pragma unroll
            for (int i = 0; i < 8; i++) {
                const int off = wid * 8192 + i * 1024;
                __builtin_amdgcn_global_load_lds(
                    (const __attribute__((address_space(1))) u32*)((const char*)gt + off + lane * 16),
                    (__attribute__((address_space(3))) u32*)((char*)bdst + off),
                    16, 0, 0);
            }
        }

        // ---- convert A(st) floats -> hi/lo bf16 fragments ----
        bf16x8 ah[4][2], al[4][2];
        #pragma unroll
        for (int fm = 0; fm < 4; fm++)
            #pragma unroll
            for (int ks = 0; ks < 2; ks++) {
                union { bf16x8 v; short s[8]; } H, L;
                #pragma unroll
                for (int j = 0; j < 8; j++)
                    split_elem(a_nxt[fm][ks][j], H.s[j], L.s[j]);
                ah[fm][ks] = H.v;
                al[fm][ks] = L.v;
            }

        // ---- load A(st+1) floats (regs free now; lands during MFMAs) ----
        if (st + 1 < NSTEP) {
            #pragma unroll
            for (int fm = 0; fm < 4; fm++)
                #pragma unroll
                for (int ks = 0; ks < 2; ks++) {
                    const float* ap = abase + (size_t)fm * 16 * DDIM + (size_t)(st + 1) * BK + ks * 32;
                    *(float4*)&a_nxt[fm][ks][0] = *(const float4*)(ap);
                    *(float4*)&a_nxt[fm][ks][4] = *(const float4*)(ap + 4);
                }
        }

        // ---- MFMA: C += Ah*Bh + Ah*Bl + Al*Bh  (96 MFMA/wave/step) ----
        #pragma unroll
        for (int fn = 0; fn < 4; fn++) {
            #pragma unroll
            for (int ks = 0; ks < 2; ks++) {
                const bf16x8 bh = *(const bf16x8*)&Blds[cur][((size_t)((0 * 2 + ks) * 8 + wn * 4 + fn) * 64 + lane) * 8];
                const bf16x8 bl = *(const bf16x8*)&Blds[cur][((size_t)((1 * 2 + ks) * 8 + wn * 4 + fn) * 64 + lane) * 8];
                #pragma unroll
                for (int fm = 0; fm < 4; fm++) {
                    acc[fm][fn] = __builtin_amdgcn_mfma_f32_16x16x32_bf16(ah[fm][ks], bh, acc[fm][fn], 0, 0, 0);
                    acc[fm][fn] = __builtin_amdgcn_mfma_f32_16x16x32_bf16(ah[fm][ks], bl, acc[fm][fn], 0, 0, 0);
                    acc[fm][fn] = __builtin_amdgcn_mfma_f32_16x16x32_bf16(al[fm][ks], bh, acc[fm][fn], 0, 0, 0);
                }
            }
        }
    }

    // ---- epilogue: fp32 partials (C/D map: col=lane&15, row=(lane>>4)*4+reg) ----
    float* pp = part + (size_t)ksp * (size_t)Btok * NEXP;
    #pragma unroll
    for (int fm = 0; fm < 4; fm++) {
        const int row0 = m0 + wm * 64 + fm * 16 + lg * 4;
        #pragma unroll
        for (int fn = 0; fn < 4; fn++) {
            const int col = nh * 128 + wn * 64 + fn * 16 + lr;
            #pragma unroll
            for (int rr = 0; rr < 4; rr++)
                pp[(size_t)(row0 + rr) * NEXP + col] = acc[fm][fn][rr];
        }
    }
}

// ---------------------------------------------------------------------------
// Kernel 2: reduce split-K partials + sigmoid + full gating, one wave per row.
// (unchanged — proven in R3/R6)
// ---------------------------------------------------------------------------
__global__ __launch_bounds__(256) void gate_kernel(
    const float* __restrict__ part, const float* __restrict__ bias,
    float* __restrict__ out_w, float* __restrict__ out_i, int B)
{
    const int lane = threadIdx.x & 63;
    const int wid  = threadIdx.x >> 6;
    const int row  = blockIdx.x * 4 + wid;
    if (row >= B) return;

    const size_t plane = (size_t)B * NEXP;
    const float* pr = part + (size_t)row * NEXP + lane * 4;
    float4 v0 = *(const float4*)(pr);
    float4 v1 = *(const float4*)(pr + plane);
    float4 v2 = *(const float4*)(pr + 2 * plane);
    float4 v3 = *(const float4*)(pr + 3 * plane);
    float sc[4] = { v0.x + v1.x + v2.x + v3.x,
                    v0.y + v1.y + v2.y + v3.y,
                    v0.z + v1.z + v2.z + v3.z,
                    v0.w + v1.w + v2.w + v3.w };
    float4 bv = *(const float4*)(bias + lane * 4);
    const float bb[4] = { bv.x, bv.y, bv.z, bv.w };

    float so[4], sb[4];
    #pragma unroll
    for (int j = 0; j < 4; j++) {
        so[j] = 1.0f / (1.0f + expf(-sc[j]));
        sb[j] = so[j] + bb[j];
    }

    // ---- group scores: sum of top-2 of sb within each 32-expert group ----
    float m1 = sb[0], m2 = -INFINITY;
    #pragma unroll
    for (int j = 1; j < 4; j++) {
        if (sb[j] > m1)      { m2 = m1; m1 = sb[j]; }
        else if (sb[j] > m2) { m2 = sb[j]; }
    }
    #pragma unroll
    for (int m = 1; m <= 4; m <<= 1) {
        float o1 = __shfl_xor(m1, m);
        float o2 = __shfl_xor(m2, m);
        float hi = fmaxf(m1, o1);
        float lo = fminf(m1, o1);
        m1 = hi;
        m2 = fmaxf(lo, fmaxf(m2, o2));
    }
    float gscore = m1 + m2;
    int g = lane >> 3;

    // ---- top-4 groups (value desc, index asc) ----
    float gs[NGRP];
    #pragma unroll
    for (int gg = 0; gg < NGRP; gg++) gs[gg] = __shfl(gscore, gg * 8);
    int rank = 0;
    #pragma unroll
    for (int gg = 0; gg < NGRP; gg++) {
        if (gg == g) continue;
        if (gs[gg] > gs[g] || (gs[gg] == gs[g] && gg < g)) rank++;
    }
    const bool selg = (rank < TOPKG);
    float mv[4];
    #pragma unroll
    for (int j = 0; j < 4; j++) mv[j] = selg ? sb[j] : -INFINITY;

    // ---- iterative top-8 wave argmax (value desc, index asc) ----
    float wsel[TOPK];
    int   isel[TOPK];
    float wsum = 0.f;
    #pragma unroll
    for (int it = 0; it < TOPK; it++) {
        float v = mv[0]; int jj = 0;
        #pragma unroll
        for (int j = 1; j < 4; j++)
            if (mv[j] > v) { v = mv[j]; jj = j; }
        int gi = (lane << 2) | jj;
        #pragma unroll
        for (int m = 1; m < 64; m <<= 1) {
            float ov = __shfl_xor(v, m);
            int   oi = __shfl_xor(gi, m);
            if (ov > v || (ov == v && oi < gi)) { v = ov; gi = oi; }
        }
        int slot = gi & 3, src = gi >> 2;
        float cand = (slot == 0) ? so[0] : (slot == 1) ? so[1] : (slot == 2) ? so[2] : so[3];
        float sval = __shfl(cand, src);
        wsel[it] = sval; isel[it] = gi; wsum += sval;
        if (lane == src) mv[slot] = -INFINITY;
    }

    if (lane == 0) {
        float scl = ROUTE_SCALE / wsum;
        #pragma unroll
        for (int it = 0; it < TOPK; it++) {
            out_w[(size_t)row * TOPK + it] = wsel[it] * scl;
            out_i[(size_t)row * TOPK + it] = (float)isel[it];
        }
    }
}

extern "C" void kernel_launch(void* const* d_in, const int* in_sizes, int n_in,
                              void* d_out, int out_size, void* d_ws, size_t ws_size,
                              hipStream_t stream)
{
    const float* x    = (const float*)d_in[0];
    const float* w    = (const float*)d_in[1];
    const float* bias = (const float*)d_in[2];
    const int B = in_sizes[0] / DDIM;           // 8192

    // ws layout: [ part: 4 * B * 256 f32 = 32 MB ][ wsp: 112*2 tiles * 32 KB = 7.34 MB ]
    float* part = (float*)d_ws;
    short* wsp  = (short*)((char*)d_ws + (size_t)KSPLIT * B * NEXP * sizeof(float));

    float* out_w = (float*)d_out;
    float* out_i = out_w + (size_t)B * TOPK;

    hipLaunchKernelGGL(wsplit_kernel, dim3(NKT), dim3(256), 0, stream, w, wsp);
    hipLaunchKernelGGL(gemm_split_kernel, dim3((B / BM) * 2 * KSPLIT), dim3(256), 0, stream,
                       x, wsp, part, B);
    hipLaunchKernelGGL(gate_kernel, dim3((B + 3) / 4), dim3(256), 0, stream,
                       part, bias, out_w, out_i, B);
}

// Round 8
// 158.174 us; speedup vs baseline: 5.5984x; 1.0817x over previous
//
#include <hip/hip_runtime.h>
#include <hip/hip_bf16.h>
#include <math.h>

#define DDIM 7168
#define NEXP 256
#define NGRP 8
#define TOPKG 4
#define TOPK 8
#define ROUTE_SCALE 2.5f

#define BM 256
#define BN 128
#define BK 64
#define KSPLIT 4
#define KPER (DDIM / KSPLIT)     // 1792
#define NSTEP (KPER / BK)        // 28
#define NKT (DDIM / BK)          // 112 global k-tiles
#define BT_ELEMS (BN * BK * 2)   // 16384 shorts = 32 KB per (kt, nh) tile

typedef __attribute__((ext_vector_type(8))) short bf16x8;
typedef __attribute__((ext_vector_type(4))) float f32x4;
typedef unsigned int u32;
typedef unsigned short ushort_t;

static __device__ __forceinline__ ushort_t bf16_rne(float f) {
    u32 b = __float_as_uint(f);
    u32 r = (b + 0x7fffu + ((b >> 16) & 1u)) >> 16;
    return (ushort_t)r;
}
static __device__ __forceinline__ float bf16_to_f32(ushort_t h) {
    return __uint_as_float(((u32)h) << 16);
}
// hi = bf16(f) via HW cvt; lo = bf16(f - hi)
static __device__ __forceinline__ void split_elem(float f, short& h, short& l) {
    union { __hip_bfloat16 b; short s; } cv;
    cv.b = __float2bfloat16(f);
    h = cv.s;
    float hf = __uint_as_float(((u32)(ushort_t)cv.s) << 16);
    cv.b = __float2bfloat16(f - hf);
    l = cv.s;
}

// ---------------------------------------------------------------------------
// Kernel 0: split w into hi/lo bf16, fragment-linear tiles per (kt, nh).
// Tile (32 KB): [split(2)][ks(2)][fn(8)][lane(64)][8 bf16]   (unchanged, proven)
// ---------------------------------------------------------------------------
__global__ __launch_bounds__(256) void wsplit_kernel(const float* __restrict__ w,
                                                     short* __restrict__ wsp)
{
    const int kt = blockIdx.x;      // 0..111
    const int e  = threadIdx.x;     // expert 0..255
    const float* wp = w + (size_t)e * DDIM + (size_t)kt * BK;
    const int nh = e >> 7, fn = (e >> 4) & 7, er = e & 15;
    short* tb = wsp + ((size_t)kt * 2 + nh) * BT_ELEMS;
    #pragma unroll
    for (int ks = 0; ks < 2; ks++) {
        #pragma unroll
        for (int jg = 0; jg < 4; jg++) {
            float f[8];
            *(float4*)&f[0] = *(const float4*)(wp + ks * 32 + jg * 8);
            *(float4*)&f[4] = *(const float4*)(wp + ks * 32 + jg * 8 + 4);
            ushort_t h[8], l[8];
            #pragma unroll
            for (int j = 0; j < 8; j++) {
                h[j] = bf16_rne(f[j]);
                l[j] = bf16_rne(f[j] - bf16_to_f32(h[j]));
            }
            const int lane = jg * 16 + er;
            *(uint4*)(tb + ((size_t)((0 * 2 + ks) * 8 + fn) * 64 + lane) * 8) = *(uint4*)h;
            *(uint4*)(tb + ((size_t)((1 * 2 + ks) * 8 + fn) * 64 + lane) * 8) = *(uint4*)l;
        }
    }
}

// ---------------------------------------------------------------------------
// Kernel 1: split-precision bf16 MFMA GEMM — counted-vmcnt pipeline (T3+T4).
// grid = 32 mt x 2 nh x 4 ksp = 256 blocks (1/CU); 512 thr = 8 waves
// (4 wm x 2 wn), wave tile 64x64, 96 MFMA/wave/step.
// B: 3-buffer LDS (96 KB), global_load_lds issued 2 steps ahead.
// Sync per step: s_waitcnt vmcnt(12) + raw s_barrier — NEVER vmcnt(0) in the
// main loop (m218: counted-vs-drain0 = +38-73%). vmcnt(12) = one full
// iteration's issue (4 B-glds + 8 A-loads per thread), so B(st) (issued two
// iterations ago) is guaranteed complete; barrier makes that cross-wave.
// WAR: B(st+2)'s destination was last READ in step st-1, whose reads are
// register-consumed before the step-st barrier that precedes the DMA issue.
// A: per-wave fp32 loads 1 step ahead into regs (64 VGPR), convert-once.
// ---------------------------------------------------------------------------
__global__ __launch_bounds__(512) void gemm_split_kernel(
    const float* __restrict__ x, const short* __restrict__ wsp,
    float* __restrict__ part, int Btok)
{
    __shared__ short Blds[3][BT_ELEMS];   // 3 x 32 KB = 96 KB

    const int bid  = blockIdx.x;
    const int mt   = bid >> 3;            // 0..31
    const int nh   = (bid >> 2) & 1;
    const int ksp  = bid & 3;
    const int m0   = mt * BM;
    const int kbase = ksp * KPER;
    const int t    = threadIdx.x;
    const int wid  = t >> 6, lane = t & 63;
    const int wm   = wid >> 1, wn = wid & 1;
    const int lr   = lane & 15, lg = lane >> 4;

    const short* wt0 = wsp + ((size_t)(ksp * NSTEP) * 2 + nh) * BT_ELEMS;
    // A: rows m0 + wm*64 + fm*16 + lr ; k = kbase + st*64 + ks*32 + lg*8
    const float* abase = x + (size_t)(m0 + wm * 64 + lr) * DDIM + kbase + lg * 8;

#define STAGE_B(stp, dst) do {                                                             \
        const short* gt_ = wt0 + (size_t)(stp) * 2 * BT_ELEMS;                             \
        _Pragma("unroll")                                                                  \
        for (int i_ = 0; i_ < 4; i_++) {                                                   \
            const int off_ = wid * 4096 + i_ * 1024;                                       \
            __builtin_amdgcn_global_load_lds(                                              \
                (const __attribute__((address_space(1))) u32*)((const char*)gt_ + off_ + lane * 16), \
                (__attribute__((address_space(3))) u32*)((char*)(dst) + off_),             \
                16, 0, 0);                                                                 \
        } } while (0)

#define LOAD_A(stp) do {                                                                   \
        _Pragma("unroll")                                                                  \
        for (int fm_ = 0; fm_ < 4; fm_++)                                                  \
            _Pragma("unroll")                                                              \
            for (int ks_ = 0; ks_ < 2; ks_++) {                                            \
                const float* ap_ = abase + (size_t)fm_ * 16 * DDIM + (size_t)(stp) * BK + ks_ * 32; \
                *(float4*)&a_cur[fm_][ks_][0] = *(const float4*)(ap_);                     \
                *(float4*)&a_cur[fm_][ks_][4] = *(const float4*)(ap_ + 4);                 \
            } } while (0)

    f32x4 acc[4][4];
    #pragma unroll
    for (int i = 0; i < 4; i++)
        #pragma unroll
        for (int j = 0; j < 4; j++) acc[i][j] = (f32x4){0.f, 0.f, 0.f, 0.f};

    float a_cur[4][2][8];

    // ---- prologue: B(0), A(0), B(1) in flight (order matters for vmcnt) ----
    STAGE_B(0, &Blds[0][0]);
    LOAD_A(0);
    STAGE_B(1, &Blds[1][0]);

    short* bp_r = &Blds[0][0];   // buffer holding B(st)
    short* bp_1 = &Blds[1][0];   // buffer holding B(st+1)
    short* bp_2 = &Blds[2][0];   // destination for B(st+2)

    for (int st = 0; st < NSTEP; st++) {
        // ---- counted wait + barrier: B(st) resident, prior reads retired ----
        asm volatile("" ::: "memory");
        if (st < NSTEP - 1) {
            asm volatile("s_waitcnt vmcnt(12)" ::: "memory");
        } else {
            asm volatile("s_waitcnt vmcnt(0)" ::: "memory");
        }
        __builtin_amdgcn_s_barrier();
        asm volatile("" ::: "memory");

        // ---- issue B(st+2) DMA (lands over the next 2 steps) ----
        if (st + 2 < NSTEP) STAGE_B(st + 2, bp_2);

        // ---- convert A(st) -> hi/lo fragments (compiler waits on A regs) ----
        bf16x8 ah[4][2], al[4][2];
        #pragma unroll
        for (int fm = 0; fm < 4; fm++)
            #pragma unroll
            for (int ks = 0; ks < 2; ks++) {
                union { bf16x8 v; short s[8]; } H, L;
                #pragma unroll
                for (int j = 0; j < 8; j++)
                    split_elem(a_cur[fm][ks][j], H.s[j], L.s[j]);
                ah[fm][ks] = H.v;
                al[fm][ks] = L.v;
            }

        // ---- issue A(st+1) loads (regs free; land during MFMAs) ----
        if (st + 1 < NSTEP) LOAD_A(st + 1);

        // ---- MFMA: C += Ah*Bh + Ah*Bl + Al*Bh  (96/wave/step) ----
        __builtin_amdgcn_s_setprio(1);
        #pragma unroll
        for (int fn = 0; fn < 4; fn++) {
            #pragma unroll
            for (int ks = 0; ks < 2; ks++) {
                const bf16x8 bh = *(const bf16x8*)&bp_r[((size_t)((0 * 2 + ks) * 8 + wn * 4 + fn) * 64 + lane) * 8];
                const bf16x8 bl = *(const bf16x8*)&bp_r[((size_t)((1 * 2 + ks) * 8 + wn * 4 + fn) * 64 + lane) * 8];
                #pragma unroll
                for (int fm = 0; fm < 4; fm++) {
                    acc[fm][fn] = __builtin_amdgcn_mfma_f32_16x16x32_bf16(ah[fm][ks], bh, acc[fm][fn], 0, 0, 0);
                    acc[fm][fn] = __builtin_amdgcn_mfma_f32_16x16x32_bf16(ah[fm][ks], bl, acc[fm][fn], 0, 0, 0);
                    acc[fm][fn] = __builtin_amdgcn_mfma_f32_16x16x32_bf16(al[fm][ks], bh, acc[fm][fn], 0, 0, 0);
                }
            }
        }
        __builtin_amdgcn_s_setprio(0);

        // ---- rotate the 3 B buffers ----
        short* tmp = bp_r; bp_r = bp_1; bp_1 = bp_2; bp_2 = tmp;
    }
#undef STAGE_B
#undef LOAD_A

    // ---- epilogue: fp32 partials (C/D map: col=lane&15, row=(lane>>4)*4+reg) ----
    float* pp = part + (size_t)ksp * (size_t)Btok * NEXP;
    #pragma unroll
    for (int fm = 0; fm < 4; fm++) {
        const int row0 = m0 + wm * 64 + fm * 16 + lg * 4;
        #pragma unroll
        for (int fn = 0; fn < 4; fn++) {
            const int col = nh * 128 + wn * 64 + fn * 16 + lr;
            #pragma unroll
            for (int rr = 0; rr < 4; rr++)
                pp[(size_t)(row0 + rr) * NEXP + col] = acc[fm][fn][rr];
        }
    }
}

// ---------------------------------------------------------------------------
// Kernel 2: reduce split-K partials + sigmoid + full gating, one wave per row.
// (unchanged — proven)
// ---------------------------------------------------------------------------
__global__ __launch_bounds__(256) void gate_kernel(
    const float* __restrict__ part, const float* __restrict__ bias,
    float* __restrict__ out_w, float* __restrict__ out_i, int B)
{
    const int lane = threadIdx.x & 63;
    const int wid  = threadIdx.x >> 6;
    const int row  = blockIdx.x * 4 + wid;
    if (row >= B) return;

    const size_t plane = (size_t)B * NEXP;
    const float* pr = part + (size_t)row * NEXP + lane * 4;
    float4 v0 = *(const float4*)(pr);
    float4 v1 = *(const float4*)(pr + plane);
    float4 v2 = *(const float4*)(pr + 2 * plane);
    float4 v3 = *(const float4*)(pr + 3 * plane);
    float sc[4] = { v0.x + v1.x + v2.x + v3.x,
                    v0.y + v1.y + v2.y + v3.y,
                    v0.z + v1.z + v2.z + v3.z,
                    v0.w + v1.w + v2.w + v3.w };
    float4 bv = *(const float4*)(bias + lane * 4);
    const float bb[4] = { bv.x, bv.y, bv.z, bv.w };

    float so[4], sb[4];
    #pragma unroll
    for (int j = 0; j < 4; j++) {
        so[j] = 1.0f / (1.0f + expf(-sc[j]));
        sb[j] = so[j] + bb[j];
    }

    // ---- group scores: sum of top-2 of sb within each 32-expert group ----
    float m1 = sb[0], m2 = -INFINITY;
    #pragma unroll
    for (int j = 1; j < 4; j++) {
        if (sb[j] > m1)      { m2 = m1; m1 = sb[j]; }
        else if (sb[j] > m2) { m2 = sb[j]; }
    }
    #pragma unroll
    for (int m = 1; m <= 4; m <<= 1) {
        float o1 = __shfl_xor(m1, m);
        float o2 = __shfl_xor(m2, m);
        float hi = fmaxf(m1, o1);
        float lo = fminf(m1, o1);
        m1 = hi;
        m2 = fmaxf(lo, fmaxf(m2, o2));
    }
    float gscore = m1 + m2;
    int g = lane >> 3;

    // ---- top-4 groups (value desc, index asc) ----
    float gs[NGRP];
    #pragma unroll
    for (int gg = 0; gg < NGRP; gg++) gs[gg] = __shfl(gscore, gg * 8);
    int rank = 0;
    #pragma unroll
    for (int gg = 0; gg < NGRP; gg++) {
        if (gg == g) continue;
        if (gs[gg] > gs[g] || (gs[gg] == gs[g] && gg < g)) rank++;
    }
    const bool selg = (rank < TOPKG);
    float mv[4];
    #pragma unroll
    for (int j = 0; j < 4; j++) mv[j] = selg ? sb[j] : -INFINITY;

    // ---- iterative top-8 wave argmax (value desc, index asc) ----
    float wsel[TOPK];
    int   isel[TOPK];
    float wsum = 0.f;
    #pragma unroll
    for (int it = 0; it < TOPK; it++) {
        float v = mv[0]; int jj = 0;
        #pragma unroll
        for (int j = 1; j < 4; j++)
            if (mv[j] > v) { v = mv[j]; jj = j; }
        int gi = (lane << 2) | jj;
        #pragma unroll
        for (int m = 1; m < 64; m <<= 1) {
            float ov = __shfl_xor(v, m);
            int   oi = __shfl_xor(gi, m);
            if (ov > v || (ov == v && oi < gi)) { v = ov; gi = oi; }
        }
        int slot = gi & 3, src = gi >> 2;
        float cand = (slot == 0) ? so[0] : (slot == 1) ? so[1] : (slot == 2) ? so[2] : so[3];
        float sval = __shfl(cand, src);
        wsel[it] = sval; isel[it] = gi; wsum += sval;
        if (lane == src) mv[slot] = -INFINITY;
    }

    if (lane == 0) {
        float scl = ROUTE_SCALE / wsum;
        #pragma unroll
        for (int it = 0; it < TOPK; it++) {
            out_w[(size_t)row * TOPK + it] = wsel[it] * scl;
            out_i[(size_t)row * TOPK + it] = (float)isel[it];
        }
    }
}

extern "C" void kernel_launch(void* const* d_in, const int* in_sizes, int n_in,
                              void* d_out, int out_size, void* d_ws, size_t ws_size,
                              hipStream_t stream)
{
    const float* x    = (const float*)d_in[0];
    const float* w    = (const float*)d_in[1];
    const float* bias = (const float*)d_in[2];
    const int B = in_sizes[0] / DDIM;           // 8192

    // ws layout: [ part: 4 * B * 256 f32 = 32 MB ][ wsp: 112*2 tiles * 32 KB = 7.34 MB ]
    float* part = (float*)d_ws;
    short* wsp  = (short*)((char*)d_ws + (size_t)KSPLIT * B * NEXP * sizeof(float));

    float* out_w = (float*)d_out;
    float* out_i = out_w + (size_t)B * TOPK;

    hipLaunchKernelGGL(wsplit_kernel, dim3(NKT), dim3(256), 0, stream, w, wsp);
    hipLaunchKernelGGL(gemm_split_kernel, dim3((B / BM) * 2 * KSPLIT), dim3(512), 0, stream,
                       x, wsp, part, B);
    hipLaunchKernelGGL(gate_kernel, dim3((B + 3) / 4), dim3(256), 0, stream,
                       part, bias, out_w, out_i, B);
}